// Round 2
// baseline (2326.044 us; speedup 1.0000x reference)
//
#include <hip/hip_runtime.h>
#include <hip/hip_bf16.h>

#define DIM 512
#define NCOLS 16384
#define PAN 64

// ---------------------------------------------------------------------------
// Stage 1: G = W^T W in f64.  G[i][j] = sum_r W[r][i]*W[r][j].
// 2x2 outputs per thread to halve cvt count. grid (16,16), block 256.
__global__ __launch_bounds__(256) void k_gram(const float* __restrict__ W,
                                              double* __restrict__ G) {
  int tx = threadIdx.x & 15, ty = threadIdx.x >> 4;
  int j0 = blockIdx.x * 32 + tx, j1 = j0 + 16;
  int i0 = blockIdx.y * 32 + ty, i1 = i0 + 16;
  double a00 = 0, a01 = 0, a10 = 0, a11 = 0;
#pragma unroll 4
  for (int r = 0; r < DIM; ++r) {
    const float* row = W + r * DIM;
    double wi0 = (double)row[i0], wi1 = (double)row[i1];
    double wj0 = (double)row[j0], wj1 = (double)row[j1];
    a00 += wi0 * wj0; a01 += wi0 * wj1;
    a10 += wi1 * wj0; a11 += wi1 * wj1;
  }
  G[i0 * DIM + j0] = a00; G[i0 * DIM + j1] = a01;
  G[i1 * DIM + j0] = a10; G[i1 * DIM + j1] = a11;
}

// ---------------------------------------------------------------------------
// Stage 2a: factor 64x64 diagonal block (panel k) in f64 on ONE wave.
// lane = row of the block, rows in registers, column broadcast via __shfl
// (no LDS -> no intra-wave memory-ordering assumptions).
__global__ __launch_bounds__(64) void k_chol_diag(double* __restrict__ G,
                                                  float* __restrict__ Lt,
                                                  int k) {
  const int lane = threadIdx.x;
  const int base = k * PAN;
  double a[64];
#pragma unroll
  for (int c = 0; c < 64; ++c) {
    int hi = lane > c ? lane : c;
    int lo = lane > c ? c : lane;
    a[c] = G[(base + hi) * DIM + base + lo];  // mirrored: only lower is valid
  }
#pragma unroll
  for (int c = 0; c < 64; ++c) {
    double dcc = __shfl(a[c], c);       // current A[c][c]
    double rs = 1.0 / sqrt(dcc);
    double Lic = a[c] * rs;             // lane's L[lane][c]  (valid lane>=c)
    if (lane >= c) {
      G[(base + lane) * DIM + base + c] = Lic;
      Lt[(base + c) * DIM + base + lane] = (float)Lic;
    }
#pragma unroll
    for (int j = c + 1; j < 64; ++j) {
      double Ljc = __shfl(Lic, j);      // L[j][c] broadcast from lane j
      a[j] -= Lic * Ljc;                // symmetric rank-1 update
    }
  }
}

// ---------------------------------------------------------------------------
// Stage 2b: panel TRSM.  rows r in [64(k+1),512): solve x * Lkk^T = A[r,panel].
// thread = row; L diag block staged in LDS; inner-product form, 4 partial accs.
__global__ __launch_bounds__(64) void k_chol_trsm(double* __restrict__ G,
                                                  float* __restrict__ Lt,
                                                  int k) {
  __shared__ double Ls[64][65];
  __shared__ double invd[64];
  const int base = k * PAN;
  const int tid = threadIdx.x;
  for (int e = tid; e < 64 * 64; e += 64) {
    int i = e >> 6, j = e & 63;
    Ls[i][j] = G[(base + i) * DIM + base + j];  // only lower is used later
  }
  __syncthreads();
  invd[tid] = 1.0 / Ls[tid][tid];
  __syncthreads();

  const int r = base + 64 + blockIdx.x * 64 + tid;
  double x[64];
#pragma unroll
  for (int j = 0; j < 64; ++j) x[j] = G[r * DIM + base + j];
#pragma unroll
  for (int j = 0; j < 64; ++j) {
    double s0 = 0, s1 = 0, s2 = 0, s3 = 0;
#pragma unroll
    for (int c = 0; c < j; ++c) {
      double t = x[c] * Ls[j][c];
      if ((c & 3) == 0) s0 += t;
      else if ((c & 3) == 1) s1 += t;
      else if ((c & 3) == 2) s2 += t;
      else s3 += t;
    }
    x[j] = (x[j] - ((s0 + s1) + (s2 + s3))) * invd[j];
  }
#pragma unroll
  for (int j = 0; j < 64; ++j) {
    G[r * DIM + base + j] = x[j];
    Lt[(base + j) * DIM + r] = (float)x[j];
  }
}

// ---------------------------------------------------------------------------
// Stage 2c: trailing Schur update (lower triangle only):
// G[i][j] -= sum_c L[i][pb+c]*L[j][pb+c]  for i,j >= 64(k+1).
__global__ __launch_bounds__(256) void k_syrk(double* __restrict__ G, int k) {
  const int off = (k + 1) * 64, pb = k * 64;
  int j = off + blockIdx.x * 16 + (threadIdx.x & 15);
  int i = off + blockIdx.y * 16 + (threadIdx.x >> 4);
  if (j > i) return;
  const double* Li = G + i * DIM + pb;
  const double* Lj = G + j * DIM + pb;
  double acc = G[i * DIM + j];
#pragma unroll 16
  for (int c = 0; c < 64; ++c) acc -= Li[c] * Lj[c];
  G[i * DIM + j] = acc;
}

// ---------------------------------------------------------------------------
// Stage 3: Minv = L^{-1} in f32, one wave per column j.
// Blocked forward substitution: coalesced GEMV over finished 64-row blocks
// (reads Lt = L^T so lanes are contiguous), then an in-register 64-step
// broadcast solve for the diagonal block.  Block loop is UNIFORM across the
// 4 waves (predicated on b>=jb, wave-uniform) so __syncthreads is legal and
// fences the per-wave ysh write->read handoff.
__global__ __launch_bounds__(256) void k_linv(const float* __restrict__ Lt,
                                              float* __restrict__ Minv) {
  __shared__ float ysh[4][DIM];
  const int lane = threadIdx.x & 63;
  const int w = threadIdx.x >> 6;
  const int j = blockIdx.x * 4 + w;
  float* y = ysh[w];
  const int jb = j >> 6;

  for (int i = lane; i < j; i += 64) Minv[i * DIM + j] = 0.f;  // upper zeros

  for (int b = 0; b < 8; ++b) {
    if (b >= jb) {                                  // wave-uniform predicate
      const int I = b * 64 + lane;
      float acc = 0.f;
      for (int c = jb * 64; c < b * 64; ++c)        // GEMV over finished blocks
        acc += Lt[c * DIM + I] * y[c];
      float lv[64];
      float diag = 1.f;
#pragma unroll
      for (int c = 0; c < 64; ++c) {
        float t = (c <= lane) ? Lt[(b * 64 + c) * DIM + I] : 0.f;
        lv[c] = t;
        if (c == lane) diag = t;
      }
      const float invLd = 1.f / diag;
      float yown = 0.f;
#pragma unroll
      for (int c = 0; c < 64; ++c) {
        if (lane == c) {
          float rhs = (I == j) ? 1.f : 0.f;
          yown = (rhs - acc) * invLd;
        }
        float bv = __shfl(yown, c);
        if (lane > c) acc += lv[c] * bv;
      }
      y[b * 64 + lane] = yown;
      if (I >= j) Minv[I * DIM + j] = yown;
    }
    __syncthreads();
  }
}

// ---------------------------------------------------------------------------
// Stage 4: U = W * Minv^T  (f32).  U[r][i] = sum_c W[r][c]*Minv[i][c].
__global__ __launch_bounds__(256) void k_formU(const float* __restrict__ W,
                                               const float* __restrict__ Minv,
                                               float* __restrict__ U) {
  int i = blockIdx.x * 16 + (threadIdx.x & 15);
  int r = blockIdx.y * 16 + (threadIdx.x >> 4);
  float acc = 0.f;
#pragma unroll 8
  for (int c = 0; c < DIM; ++c) acc += W[r * DIM + c] * Minv[i * DIM + c];
  U[r * DIM + i] = acc;
}

// ---------------------------------------------------------------------------
// Stage 5: P = U * diag(sigmoid(Dp)) * U^T, output bf16 (RNE).
__global__ __launch_bounds__(256) void k_formP(const float* __restrict__ U,
                                               const float* __restrict__ Dp,
                                               unsigned short* __restrict__ P) {
  __shared__ float dsh[DIM];
  for (int t = threadIdx.x; t < DIM; t += 256)
    dsh[t] = 1.f / (1.f + __expf(-Dp[t]));
  __syncthreads();
  int j = blockIdx.x * 16 + (threadIdx.x & 15);
  int i = blockIdx.y * 16 + (threadIdx.x >> 4);
  float acc = 0.f;
#pragma unroll 8
  for (int c = 0; c < DIM; ++c)
    acc += dsh[c] * U[i * DIM + c] * U[j * DIM + c];
  unsigned u = __builtin_bit_cast(unsigned, acc);
  u += 0x7FFFu + ((u >> 16) & 1u);
  P[i * DIM + j] = (unsigned short)(u >> 16);
}

// ---------------------------------------------------------------------------
// Stage 6: out = P @ x  via bf16 MFMA.  M=512 (whole M per block), N tile 64,
// BK=32.  Reg-staged double buffer (T14 pattern): global->reg prefetch
// overlaps compute; single LDS buffer (45KB).
typedef __bf16 bf16x8 __attribute__((ext_vector_type(8)));
typedef float f32x4 __attribute__((ext_vector_type(4)));

__device__ __forceinline__ unsigned short f2bf(float f) {
  unsigned u = __builtin_bit_cast(unsigned, f);
  u += 0x7FFFu + ((u >> 16) & 1u);
  return (unsigned short)(u >> 16);
}

__global__ __launch_bounds__(512) void k_gemm(const unsigned short* __restrict__ P,
                                              const float* __restrict__ X,
                                              float* __restrict__ out) {
  __shared__ unsigned short As[DIM][40];  // [m][k] bf16, padded (stride 80B)
  __shared__ unsigned short Bs[64][40];   // [n][k] bf16
  const int tid = threadIdx.x;
  const int lane = tid & 63;
  const int w = tid >> 6;      // wave 0..7 -> 64-row slab of M
  const int bn = blockIdx.x * 64;
  const int kk = tid >> 4;     // 0..31 (k within tile)
  const int nq = tid & 15;     // n-quad

  const unsigned short* prow = P + tid * DIM;  // this thread stages P row tid
  uint4 a0 = *(const uint4*)(prow + 0);
  uint4 a1 = *(const uint4*)(prow + 8);
  uint4 a2 = *(const uint4*)(prow + 16);
  uint4 a3 = *(const uint4*)(prow + 24);
  float4 bx = *(const float4*)(X + kk * NCOLS + bn + nq * 4);

  f32x4 acc[4][4];
#pragma unroll
  for (int mf = 0; mf < 4; ++mf)
#pragma unroll
    for (int nf = 0; nf < 4; ++nf)
      acc[mf][nf] = (f32x4){0.f, 0.f, 0.f, 0.f};

#pragma unroll 1
  for (int t = 0; t < 16; ++t) {
    __syncthreads();  // everyone done reading previous tile
    *(uint4*)&As[tid][0] = a0;
    *(uint4*)&As[tid][8] = a1;
    *(uint4*)&As[tid][16] = a2;
    *(uint4*)&As[tid][24] = a3;
    Bs[nq * 4 + 0][kk] = f2bf(bx.x);
    Bs[nq * 4 + 1][kk] = f2bf(bx.y);
    Bs[nq * 4 + 2][kk] = f2bf(bx.z);
    Bs[nq * 4 + 3][kk] = f2bf(bx.w);
    if (t < 15) {  // prefetch next tile into regs; latency hides under MFMA
      const unsigned short* pn = prow + (t + 1) * 32;
      a0 = *(const uint4*)(pn + 0);
      a1 = *(const uint4*)(pn + 8);
      a2 = *(const uint4*)(pn + 16);
      a3 = *(const uint4*)(pn + 24);
      bx = *(const float4*)(X + ((t + 1) * 32 + kk) * NCOLS + bn + nq * 4);
    }
    __syncthreads();
    bf16x8 af[4], bf[4];
#pragma unroll
    for (int mf = 0; mf < 4; ++mf)
      af[mf] = *(const bf16x8*)&As[w * 64 + mf * 16 + (lane & 15)][(lane >> 4) * 8];
#pragma unroll
    for (int nf = 0; nf < 4; ++nf)
      bf[nf] = *(const bf16x8*)&Bs[nf * 16 + (lane & 15)][(lane >> 4) * 8];
#pragma unroll
    for (int mf = 0; mf < 4; ++mf)
#pragma unroll
      for (int nf = 0; nf < 4; ++nf)
        acc[mf][nf] = __builtin_amdgcn_mfma_f32_16x16x32_bf16(af[mf], bf[nf],
                                                              acc[mf][nf], 0, 0, 0);
  }

  // C/D layout (m89-verified): col = lane&15, row = (lane>>4)*4 + reg
#pragma unroll
  for (int mf = 0; mf < 4; ++mf)
#pragma unroll
    for (int nf = 0; nf < 4; ++nf)
#pragma unroll
      for (int r = 0; r < 4; ++r) {
        int row = w * 64 + mf * 16 + (lane >> 4) * 4 + r;
        int col = bn + nf * 16 + (lane & 15);
        out[row * NCOLS + col] = acc[mf][nf][r];
      }
}

// ---------------------------------------------------------------------------
extern "C" void kernel_launch(void* const* d_in, const int* in_sizes, int n_in,
                              void* d_out, int out_size, void* d_ws, size_t ws_size,
                              hipStream_t stream) {
  const float* X = (const float*)d_in[0];
  const float* W = (const float*)d_in[1];
  const float* Dp = (const float*)d_in[2];
  float* out = (float*)d_out;

  char* ws = (char*)d_ws;
  double* G = (double*)ws;                          // 2 MB: Gram -> L (f64)
  float* Lt = (float*)(ws + (2u << 20));            // 1 MB: L^T (f32)
  float* Minv = (float*)(ws + (3u << 20));          // 1 MB: L^-1 (f32)
  float* U = (float*)(ws + (4u << 20));             // 1 MB
  unsigned short* P = (unsigned short*)(ws + (5u << 20));  // 0.5 MB bf16

  k_gram<<<dim3(16, 16), 256, 0, stream>>>(W, G);
  for (int k = 0; k < 8; ++k) {
    k_chol_diag<<<1, 64, 0, stream>>>(G, Lt, k);
    int T = 7 - k;
    if (T > 0) {
      k_chol_trsm<<<T, 64, 0, stream>>>(G, Lt, k);
      int m = T * 64;
      k_syrk<<<dim3(m / 16, m / 16), 256, 0, stream>>>(G, k);
    }
  }
  k_linv<<<128, 256, 0, stream>>>(Lt, Minv);
  k_formU<<<dim3(32, 32), 256, 0, stream>>>(W, Minv, U);
  k_formP<<<dim3(32, 32), 256, 0, stream>>>(U, Dp, P);
  k_gemm<<<NCOLS / 64, 512, 0, stream>>>(P, X, out);
}

// Round 3
// 2022.309 us; speedup vs baseline: 1.1502x; 1.1502x over previous
//
#include <hip/hip_runtime.h>
#include <hip/hip_bf16.h>

#define DIM 512
#define NCOLS 16384
#define PAN 64

// ---------------------------------------------------------------------------
// Stage 1: G = W^T W in f64.  G[i][j] = sum_r W[r][i]*W[r][j].
// 2x2 outputs per thread to halve cvt count. grid (16,16), block 256.
__global__ __launch_bounds__(256) void k_gram(const float* __restrict__ W,
                                              double* __restrict__ G) {
  int tx = threadIdx.x & 15, ty = threadIdx.x >> 4;
  int j0 = blockIdx.x * 32 + tx, j1 = j0 + 16;
  int i0 = blockIdx.y * 32 + ty, i1 = i0 + 16;
  double a00 = 0, a01 = 0, a10 = 0, a11 = 0;
#pragma unroll 4
  for (int r = 0; r < DIM; ++r) {
    const float* row = W + r * DIM;
    double wi0 = (double)row[i0], wi1 = (double)row[i1];
    double wj0 = (double)row[j0], wj1 = (double)row[j1];
    a00 += wi0 * wj0; a01 += wi0 * wj1;
    a10 += wi1 * wj0; a11 += wi1 * wj1;
  }
  G[i0 * DIM + j0] = a00; G[i0 * DIM + j1] = a01;
  G[i1 * DIM + j0] = a10; G[i1 * DIM + j1] = a11;
}

// ---------------------------------------------------------------------------
// Stage 2a: factor 64x64 diagonal block (panel k) in f64 on ONE wave.
// REWRITE (r2): block lives in LDS (64x65 f64 = 33KB), NOT per-lane registers
// — the register version spilled (VGPR=256, 800KB scratch traffic, 396µs).
// lane = row.  Column-c reads are LDS broadcasts (uniform addr).  The trailing
// update reads only UNSCALED column c (never written during step c) -> no
// intra-step RAW hazard; cross-step ordering = per-wave DS program order.
__global__ __launch_bounds__(64) void k_chol_diag(double* __restrict__ G,
                                                  float* __restrict__ Lt,
                                                  int k) {
  __shared__ double A[64][65];
  const int lane = threadIdx.x;
  const int base = k * PAN;
  // Coalesced load of the full 64x64 square (upper part is stale garbage in G
  // for k>0; only the lower triangle is ever read below).
#pragma unroll 8
  for (int r = 0; r < 64; ++r)
    A[r][lane] = G[(base + r) * DIM + base + lane];
  __syncthreads();

#pragma unroll 1
  for (int c = 0; c < 64; ++c) {
    double dcc = A[c][c];               // uniform-address broadcast
    double rs = 1.0 / sqrt(dcc);
    double Lic = A[lane][c] * rs;       // lane's L[lane][c] (valid lane>=c)
    if (lane >= c) {
      G[(base + lane) * DIM + base + c] = Lic;
      Lt[(base + c) * DIM + base + lane] = (float)Lic;
    }
#pragma unroll 4
    for (int j = c + 1; j < 64; ++j) {
      double Ljc = A[j][c] * rs;        // unscaled col c (never overwritten)
      if (lane >= j) A[lane][j] -= Lic * Ljc;
    }
  }
}

// ---------------------------------------------------------------------------
// Stage 2b: panel TRSM.  rows r in [64(k+1),512): solve x * Lkk^T = A[r,panel].
// thread = row; L diag block staged in LDS; inner-product form, 4 partial accs.
__global__ __launch_bounds__(64) void k_chol_trsm(double* __restrict__ G,
                                                  float* __restrict__ Lt,
                                                  int k) {
  __shared__ double Ls[64][65];
  __shared__ double invd[64];
  const int base = k * PAN;
  const int tid = threadIdx.x;
  for (int e = tid; e < 64 * 64; e += 64) {
    int i = e >> 6, j = e & 63;
    Ls[i][j] = G[(base + i) * DIM + base + j];  // only lower is used later
  }
  __syncthreads();
  invd[tid] = 1.0 / Ls[tid][tid];
  __syncthreads();

  const int r = base + 64 + blockIdx.x * 64 + tid;
  double x[64];
#pragma unroll
  for (int j = 0; j < 64; ++j) x[j] = G[r * DIM + base + j];
#pragma unroll
  for (int j = 0; j < 64; ++j) {
    double s0 = 0, s1 = 0, s2 = 0, s3 = 0;
#pragma unroll
    for (int c = 0; c < j; ++c) {
      double t = x[c] * Ls[j][c];
      if ((c & 3) == 0) s0 += t;
      else if ((c & 3) == 1) s1 += t;
      else if ((c & 3) == 2) s2 += t;
      else s3 += t;
    }
    x[j] = (x[j] - ((s0 + s1) + (s2 + s3))) * invd[j];
  }
#pragma unroll
  for (int j = 0; j < 64; ++j) {
    G[r * DIM + base + j] = x[j];
    Lt[(base + j) * DIM + r] = (float)x[j];
  }
}

// ---------------------------------------------------------------------------
// Stage 2c: trailing Schur update (lower triangle only):
// G[i][j] -= sum_c L[i][pb+c]*L[j][pb+c]  for i,j >= 64(k+1).
__global__ __launch_bounds__(256) void k_syrk(double* __restrict__ G, int k) {
  const int off = (k + 1) * 64, pb = k * 64;
  int j = off + blockIdx.x * 16 + (threadIdx.x & 15);
  int i = off + blockIdx.y * 16 + (threadIdx.x >> 4);
  if (j > i) return;
  const double* Li = G + i * DIM + pb;
  const double* Lj = G + j * DIM + pb;
  double acc = G[i * DIM + j];
#pragma unroll 16
  for (int c = 0; c < 64; ++c) acc -= Li[c] * Lj[c];
  G[i * DIM + j] = acc;
}

// ---------------------------------------------------------------------------
// Stage 3: Minv = L^{-1} in f32, one wave per column j.
// Blocked forward substitution: coalesced GEMV over finished 64-row blocks
// (reads Lt = L^T so lanes are contiguous), then an in-register 64-step
// broadcast solve for the diagonal block.  Block loop is UNIFORM across the
// 4 waves (predicated on b>=jb, wave-uniform) so __syncthreads is legal and
// fences the per-wave ysh write->read handoff.
__global__ __launch_bounds__(256) void k_linv(const float* __restrict__ Lt,
                                              float* __restrict__ Minv) {
  __shared__ float ysh[4][DIM];
  const int lane = threadIdx.x & 63;
  const int w = threadIdx.x >> 6;
  const int j = blockIdx.x * 4 + w;
  float* y = ysh[w];
  const int jb = j >> 6;

  for (int i = lane; i < j; i += 64) Minv[i * DIM + j] = 0.f;  // upper zeros

  for (int b = 0; b < 8; ++b) {
    if (b >= jb) {                                  // wave-uniform predicate
      const int I = b * 64 + lane;
      float acc = 0.f;
      for (int c = jb * 64; c < b * 64; ++c)        // GEMV over finished blocks
        acc += Lt[c * DIM + I] * y[c];
      float lv[64];
      float diag = 1.f;
#pragma unroll
      for (int c = 0; c < 64; ++c) {
        float t = (c <= lane) ? Lt[(b * 64 + c) * DIM + I] : 0.f;
        lv[c] = t;
        if (c == lane) diag = t;
      }
      const float invLd = 1.f / diag;
      float yown = 0.f;
#pragma unroll
      for (int c = 0; c < 64; ++c) {
        if (lane == c) {
          float rhs = (I == j) ? 1.f : 0.f;
          yown = (rhs - acc) * invLd;
        }
        float bv = __shfl(yown, c);
        if (lane > c) acc += lv[c] * bv;
      }
      y[b * 64 + lane] = yown;
      if (I >= j) Minv[I * DIM + j] = yown;
    }
    __syncthreads();
  }
}

// ---------------------------------------------------------------------------
// Stage 4: U = W * Minv^T  (f32).  U[r][i] = sum_c W[r][c]*Minv[i][c].
__global__ __launch_bounds__(256) void k_formU(const float* __restrict__ W,
                                               const float* __restrict__ Minv,
                                               float* __restrict__ U) {
  int i = blockIdx.x * 16 + (threadIdx.x & 15);
  int r = blockIdx.y * 16 + (threadIdx.x >> 4);
  float acc = 0.f;
#pragma unroll 8
  for (int c = 0; c < DIM; ++c) acc += W[r * DIM + c] * Minv[i * DIM + c];
  U[r * DIM + i] = acc;
}

// ---------------------------------------------------------------------------
// Stage 5: P = U * diag(sigmoid(Dp)) * U^T, output bf16 (RNE).
__global__ __launch_bounds__(256) void k_formP(const float* __restrict__ U,
                                               const float* __restrict__ Dp,
                                               unsigned short* __restrict__ P) {
  __shared__ float dsh[DIM];
  for (int t = threadIdx.x; t < DIM; t += 256)
    dsh[t] = 1.f / (1.f + __expf(-Dp[t]));
  __syncthreads();
  int j = blockIdx.x * 16 + (threadIdx.x & 15);
  int i = blockIdx.y * 16 + (threadIdx.x >> 4);
  float acc = 0.f;
#pragma unroll 8
  for (int c = 0; c < DIM; ++c)
    acc += dsh[c] * U[i * DIM + c] * U[j * DIM + c];
  unsigned u = __builtin_bit_cast(unsigned, acc);
  u += 0x7FFFu + ((u >> 16) & 1u);
  P[i * DIM + j] = (unsigned short)(u >> 16);
}

// ---------------------------------------------------------------------------
// Stage 6: out = P @ x  via bf16 MFMA.  M=512 (whole M per block), N tile 64,
// BK=32.  Reg-staged double buffer (T14 pattern): global->reg prefetch
// overlaps compute; single LDS buffer (45KB).
typedef __bf16 bf16x8 __attribute__((ext_vector_type(8)));
typedef float f32x4 __attribute__((ext_vector_type(4)));

__device__ __forceinline__ unsigned short f2bf(float f) {
  unsigned u = __builtin_bit_cast(unsigned, f);
  u += 0x7FFFu + ((u >> 16) & 1u);
  return (unsigned short)(u >> 16);
}

__global__ __launch_bounds__(512) void k_gemm(const unsigned short* __restrict__ P,
                                              const float* __restrict__ X,
                                              float* __restrict__ out) {
  __shared__ unsigned short As[DIM][40];  // [m][k] bf16, padded (stride 80B)
  __shared__ unsigned short Bs[64][40];   // [n][k] bf16
  const int tid = threadIdx.x;
  const int lane = tid & 63;
  const int w = tid >> 6;      // wave 0..7 -> 64-row slab of M
  const int bn = blockIdx.x * 64;
  const int kk = tid >> 4;     // 0..31 (k within tile)
  const int nq = tid & 15;     // n-quad

  const unsigned short* prow = P + tid * DIM;  // this thread stages P row tid
  uint4 a0 = *(const uint4*)(prow + 0);
  uint4 a1 = *(const uint4*)(prow + 8);
  uint4 a2 = *(const uint4*)(prow + 16);
  uint4 a3 = *(const uint4*)(prow + 24);
  float4 bx = *(const float4*)(X + kk * NCOLS + bn + nq * 4);

  f32x4 acc[4][4];
#pragma unroll
  for (int mf = 0; mf < 4; ++mf)
#pragma unroll
    for (int nf = 0; nf < 4; ++nf)
      acc[mf][nf] = (f32x4){0.f, 0.f, 0.f, 0.f};

#pragma unroll 1
  for (int t = 0; t < 16; ++t) {
    __syncthreads();  // everyone done reading previous tile
    *(uint4*)&As[tid][0] = a0;
    *(uint4*)&As[tid][8] = a1;
    *(uint4*)&As[tid][16] = a2;
    *(uint4*)&As[tid][24] = a3;
    Bs[nq * 4 + 0][kk] = f2bf(bx.x);
    Bs[nq * 4 + 1][kk] = f2bf(bx.y);
    Bs[nq * 4 + 2][kk] = f2bf(bx.z);
    Bs[nq * 4 + 3][kk] = f2bf(bx.w);
    if (t < 15) {  // prefetch next tile into regs; latency hides under MFMA
      const unsigned short* pn = prow + (t + 1) * 32;
      a0 = *(const uint4*)(pn + 0);
      a1 = *(const uint4*)(pn + 8);
      a2 = *(const uint4*)(pn + 16);
      a3 = *(const uint4*)(pn + 24);
      bx = *(const float4*)(X + ((t + 1) * 32 + kk) * NCOLS + bn + nq * 4);
    }
    __syncthreads();
    bf16x8 af[4], bf[4];
#pragma unroll
    for (int mf = 0; mf < 4; ++mf)
      af[mf] = *(const bf16x8*)&As[w * 64 + mf * 16 + (lane & 15)][(lane >> 4) * 8];
#pragma unroll
    for (int nf = 0; nf < 4; ++nf)
      bf[nf] = *(const bf16x8*)&Bs[nf * 16 + (lane & 15)][(lane >> 4) * 8];
#pragma unroll
    for (int mf = 0; mf < 4; ++mf)
#pragma unroll
      for (int nf = 0; nf < 4; ++nf)
        acc[mf][nf] = __builtin_amdgcn_mfma_f32_16x16x32_bf16(af[mf], bf[nf],
                                                              acc[mf][nf], 0, 0, 0);
  }

  // C/D layout (m89-verified): col = lane&15, row = (lane>>4)*4 + reg
#pragma unroll
  for (int mf = 0; mf < 4; ++mf)
#pragma unroll
    for (int nf = 0; nf < 4; ++nf)
#pragma unroll
      for (int r = 0; r < 4; ++r) {
        int row = w * 64 + mf * 16 + (lane >> 4) * 4 + r;
        int col = bn + nf * 16 + (lane & 15);
        out[row * NCOLS + col] = acc[mf][nf][r];
      }
}

// ---------------------------------------------------------------------------
extern "C" void kernel_launch(void* const* d_in, const int* in_sizes, int n_in,
                              void* d_out, int out_size, void* d_ws, size_t ws_size,
                              hipStream_t stream) {
  const float* X = (const float*)d_in[0];
  const float* W = (const float*)d_in[1];
  const float* Dp = (const float*)d_in[2];
  float* out = (float*)d_out;

  char* ws = (char*)d_ws;
  double* G = (double*)ws;                          // 2 MB: Gram -> L (f64)
  float* Lt = (float*)(ws + (2u << 20));            // 1 MB: L^T (f32)
  float* Minv = (float*)(ws + (3u << 20));          // 1 MB: L^-1 (f32)
  float* U = (float*)(ws + (4u << 20));             // 1 MB
  unsigned short* P = (unsigned short*)(ws + (5u << 20));  // 0.5 MB bf16

  k_gram<<<dim3(16, 16), 256, 0, stream>>>(W, G);
  for (int k = 0; k < 8; ++k) {
    k_chol_diag<<<1, 64, 0, stream>>>(G, Lt, k);
    int T = 7 - k;
    if (T > 0) {
      k_chol_trsm<<<T, 64, 0, stream>>>(G, Lt, k);
      int m = T * 64;
      k_syrk<<<dim3(m / 16, m / 16), 256, 0, stream>>>(G, k);
    }
  }
  k_linv<<<128, 256, 0, stream>>>(Lt, Minv);
  k_formU<<<dim3(32, 32), 256, 0, stream>>>(W, Minv, U);
  k_formP<<<dim3(32, 32), 256, 0, stream>>>(U, Dp, P);
  k_gemm<<<NCOLS / 64, 512, 0, stream>>>(P, X, out);
}

// Round 4
// 906.364 us; speedup vs baseline: 2.5663x; 2.2312x over previous
//
#include <hip/hip_runtime.h>
#include <hip/hip_bf16.h>

#define DIM 512
#define NCOLS 16384

// ---------------------------------------------------------------------------
// Stage 1: G = W^T W in f64.  G[i][j] = sum_r W[r][i]*W[r][j].
__global__ __launch_bounds__(256) void k_gram(const float* __restrict__ W,
                                              double* __restrict__ G) {
  int tx = threadIdx.x & 15, ty = threadIdx.x >> 4;
  int j0 = blockIdx.x * 32 + tx, j1 = j0 + 16;
  int i0 = blockIdx.y * 32 + ty, i1 = i0 + 16;
  double a00 = 0, a01 = 0, a10 = 0, a11 = 0;
#pragma unroll 4
  for (int r = 0; r < DIM; ++r) {
    const float* row = W + r * DIM;
    double wi0 = (double)row[i0], wi1 = (double)row[i1];
    double wj0 = (double)row[j0], wj1 = (double)row[j1];
    a00 += wi0 * wj0; a01 += wi0 * wj1;
    a10 += wi1 * wj0; a11 += wi1 * wj1;
  }
  G[i0 * DIM + j0] = a00; G[i0 * DIM + j1] = a01;
  G[i1 * DIM + j0] = a10; G[i1 * DIM + j1] = a11;
}

// ---------------------------------------------------------------------------
// Stage 2 (r4 REWRITE): fused per-panel kernel, ONE workgroup of 512 threads.
//  Phase A: factor the 64x64 diag block in LDS, element-parallel, ONE
//           __syncthreads per column (64 barriers total) — replaces the
//           single-wave dependent-LDS-chain version (~100µs -> ~6µs).
//  Phase B: TRSM of the rows below (row-per-thread, static-unrolled x[64],
//           reusing the LDS diag block; no reload, no extra launch).
// Hazard notes: at step c, updates write only cols > c and read raw col c;
// the post-update barrier orders update(c) vs step c+1; the col-c scale
// touches only col c, disjoint from everything step c+1 reads/writes, so no
// second barrier is needed.
__global__ __launch_bounds__(512) void k_panel(double* __restrict__ G,
                                               float* __restrict__ Lf,
                                               int k) {
  __shared__ double A[64][65];
  __shared__ double invd[64];
  const int tid = threadIdx.x;
  const int base = k * 64;

  for (int e = tid; e < 4096; e += 512) {
    int i = e >> 6, j = e & 63;
    A[i][j] = G[(base + i) * DIM + base + j];  // upper may be stale; unused
  }
  __syncthreads();

#pragma unroll 1
  for (int c = 0; c < 64; ++c) {
    double inv = 1.0 / A[c][c];          // uniform LDS read (post-barrier)
    // trailing update, raw column c: A[i][j] -= L[i][c]*L[j][c]
#pragma unroll
    for (int q = 0; q < 8; ++q) {
      int e = q * 512 + tid;
      int i = e >> 6, j = e & 63;
      if (j > c && i >= j)
        A[i][j] -= A[i][c] * (A[j][c] * inv);
    }
    __syncthreads();
    double rs = sqrt(inv);               // 1/sqrt(dcc)
    if (tid == c) invd[c] = rs;
    if (tid < 64 && tid >= c) A[tid][c] *= rs;   // col c -> final L[:,c]
  }
  __syncthreads();  // scale(63) + invd visible to everyone

  // write diag block of L to Lf (f32); zero its upper for clean consumers
  for (int e = tid; e < 4096; e += 512) {
    int i = e >> 6, j = e & 63;
    Lf[(base + i) * DIM + base + j] = (i >= j) ? (float)A[i][j] : 0.f;
  }

  // Phase B: TRSM rows below: solve x * Lkk^T = G[r, panel]
  const int r = base + 64 + tid;
  if (r < DIM) {
    double x[64];
#pragma unroll
    for (int j = 0; j < 64; ++j) x[j] = G[r * DIM + base + j];
#pragma unroll
    for (int j = 0; j < 64; ++j) {
      double s0 = 0, s1 = 0, s2 = 0, s3 = 0;
#pragma unroll
      for (int c = 0; c < j; ++c) {
        double t = x[c] * A[j][c];
        if ((c & 3) == 0) s0 += t;
        else if ((c & 3) == 1) s1 += t;
        else if ((c & 3) == 2) s2 += t;
        else s3 += t;
      }
      x[j] = (x[j] - ((s0 + s1) + (s2 + s3))) * invd[j];
    }
#pragma unroll
    for (int j = 0; j < 64; ++j) {
      G[r * DIM + base + j] = x[j];            // f64 for k_syrk
      Lf[r * DIM + base + j] = (float)x[j];    // f32 for dinv/comb
    }
  }
}

// ---------------------------------------------------------------------------
// Stage 2c: trailing Schur update (lower triangle only).
__global__ __launch_bounds__(256) void k_syrk(double* __restrict__ G, int k) {
  const int off = (k + 1) * 64, pb = k * 64;
  int j = off + blockIdx.x * 16 + (threadIdx.x & 15);
  int i = off + blockIdx.y * 16 + (threadIdx.x >> 4);
  if (j > i) return;
  const double* Li = G + i * DIM + pb;
  const double* Lj = G + j * DIM + pb;
  double acc = G[i * DIM + j];
#pragma unroll 16
  for (int c = 0; c < 64; ++c) acc -= Li[c] * Lj[c];
  G[i * DIM + j] = acc;
}

// ---------------------------------------------------------------------------
// Stage 3a: invert the 8 diagonal 64x64 blocks of L (f32).  One block per
// 64x64; lane = column j; forward substitution with static triangular unroll
// (y[] static-indexed -> registers); L reads are uniform LDS broadcasts.
__global__ __launch_bounds__(64) void k_dinv(const float* __restrict__ Lf,
                                             float* __restrict__ Minv) {
  __shared__ float Ld[64][65];
  const int lane = threadIdx.x;
  const int b = blockIdx.x * 64;
  for (int r = 0; r < 64; ++r) Ld[r][lane] = Lf[(b + r) * DIM + b + lane];
  __syncthreads();
  float y[64];
#pragma unroll
  for (int i = 0; i < 64; ++i) {
    float s = (i == lane) ? 1.f : 0.f;
#pragma unroll
    for (int c = 0; c < i; ++c) s -= Ld[i][c] * y[c];  // y[c]=0 for c<lane
    y[i] = s / Ld[i][i];
  }
  for (int i = 0; i < 64; ++i) Minv[(b + i) * DIM + b + lane] = y[i];
}

// ---------------------------------------------------------------------------
// Stage 3b: recursive combine.  For [[A,0],[B,C]]^{-1}, off-diag = -Cinv*B*Ainv.
// Two GEMM sweeps per level with temp T.  Level l: n=64<<l, pairs P=4>>l.
__global__ __launch_bounds__(256) void k_combT(const float* __restrict__ Lf,
                                               const float* __restrict__ Minv,
                                               float* __restrict__ T, int n) {
  const int p = blockIdx.z;
  const int rb = p * 2 * n + n, cb = p * 2 * n;
  const int j = blockIdx.x * 16 + (threadIdx.x & 15);
  const int i = blockIdx.y * 16 + (threadIdx.x >> 4);
  float acc = 0.f;
#pragma unroll 4
  for (int c = 0; c < n; ++c)
    acc += Lf[(rb + i) * DIM + cb + c] * Minv[(cb + c) * DIM + cb + j];
  T[p * n * n + i * n + j] = acc;
}

__global__ __launch_bounds__(256) void k_combO(float* __restrict__ Minv,
                                               const float* __restrict__ T, int n) {
  const int p = blockIdx.z;
  const int rb = p * 2 * n + n, cb = p * 2 * n;
  const int j = blockIdx.x * 16 + (threadIdx.x & 15);
  const int i = blockIdx.y * 16 + (threadIdx.x >> 4);
  float acc = 0.f;
#pragma unroll 4
  for (int c = 0; c < n; ++c)
    acc += Minv[(rb + i) * DIM + rb + c] * T[p * n * n + c * n + j];
  Minv[(rb + i) * DIM + cb + j] = -acc;   // reads cols rb.., writes cols cb..: disjoint
}

// ---------------------------------------------------------------------------
// Stage 4: U = W * Minv^T  (f32).  U[r][i] = sum_c W[r][c]*Minv[i][c].
__global__ __launch_bounds__(256) void k_formU(const float* __restrict__ W,
                                               const float* __restrict__ Minv,
                                               float* __restrict__ U) {
  int i = blockIdx.x * 16 + (threadIdx.x & 15);
  int r = blockIdx.y * 16 + (threadIdx.x >> 4);
  float acc = 0.f;
#pragma unroll 8
  for (int c = 0; c < DIM; ++c) acc += W[r * DIM + c] * Minv[i * DIM + c];
  U[r * DIM + i] = acc;
}

// ---------------------------------------------------------------------------
// Stage 5: P = U * diag(sigmoid(Dp)) * U^T, output bf16 (RNE).
__global__ __launch_bounds__(256) void k_formP(const float* __restrict__ U,
                                               const float* __restrict__ Dp,
                                               unsigned short* __restrict__ P) {
  __shared__ float dsh[DIM];
  for (int t = threadIdx.x; t < DIM; t += 256)
    dsh[t] = 1.f / (1.f + __expf(-Dp[t]));
  __syncthreads();
  int j = blockIdx.x * 16 + (threadIdx.x & 15);
  int i = blockIdx.y * 16 + (threadIdx.x >> 4);
  float acc = 0.f;
#pragma unroll 8
  for (int c = 0; c < DIM; ++c)
    acc += dsh[c] * U[i * DIM + c] * U[j * DIM + c];
  unsigned u = __builtin_bit_cast(unsigned, acc);
  u += 0x7FFFu + ((u >> 16) & 1u);
  P[i * DIM + j] = (unsigned short)(u >> 16);
}

// ---------------------------------------------------------------------------
// Stage 6: out = P @ x via bf16 MFMA (unchanged from r3).
typedef __bf16 bf16x8 __attribute__((ext_vector_type(8)));
typedef float f32x4 __attribute__((ext_vector_type(4)));

__device__ __forceinline__ unsigned short f2bf(float f) {
  unsigned u = __builtin_bit_cast(unsigned, f);
  u += 0x7FFFu + ((u >> 16) & 1u);
  return (unsigned short)(u >> 16);
}

__global__ __launch_bounds__(512) void k_gemm(const unsigned short* __restrict__ P,
                                              const float* __restrict__ X,
                                              float* __restrict__ out) {
  __shared__ unsigned short As[DIM][40];
  __shared__ unsigned short Bs[64][40];
  const int tid = threadIdx.x;
  const int lane = tid & 63;
  const int w = tid >> 6;
  const int bn = blockIdx.x * 64;
  const int kk = tid >> 4;
  const int nq = tid & 15;

  const unsigned short* prow = P + tid * DIM;
  uint4 a0 = *(const uint4*)(prow + 0);
  uint4 a1 = *(const uint4*)(prow + 8);
  uint4 a2 = *(const uint4*)(prow + 16);
  uint4 a3 = *(const uint4*)(prow + 24);
  float4 bx = *(const float4*)(X + kk * NCOLS + bn + nq * 4);

  f32x4 acc[4][4];
#pragma unroll
  for (int mf = 0; mf < 4; ++mf)
#pragma unroll
    for (int nf = 0; nf < 4; ++nf)
      acc[mf][nf] = (f32x4){0.f, 0.f, 0.f, 0.f};

#pragma unroll 1
  for (int t = 0; t < 16; ++t) {
    __syncthreads();
    *(uint4*)&As[tid][0] = a0;
    *(uint4*)&As[tid][8] = a1;
    *(uint4*)&As[tid][16] = a2;
    *(uint4*)&As[tid][24] = a3;
    Bs[nq * 4 + 0][kk] = f2bf(bx.x);
    Bs[nq * 4 + 1][kk] = f2bf(bx.y);
    Bs[nq * 4 + 2][kk] = f2bf(bx.z);
    Bs[nq * 4 + 3][kk] = f2bf(bx.w);
    if (t < 15) {
      const unsigned short* pn = prow + (t + 1) * 32;
      a0 = *(const uint4*)(pn + 0);
      a1 = *(const uint4*)(pn + 8);
      a2 = *(const uint4*)(pn + 16);
      a3 = *(const uint4*)(pn + 24);
      bx = *(const float4*)(X + ((t + 1) * 32 + kk) * NCOLS + bn + nq * 4);
    }
    __syncthreads();
    bf16x8 af[4], bf[4];
#pragma unroll
    for (int mf = 0; mf < 4; ++mf)
      af[mf] = *(const bf16x8*)&As[w * 64 + mf * 16 + (lane & 15)][(lane >> 4) * 8];
#pragma unroll
    for (int nf = 0; nf < 4; ++nf)
      bf[nf] = *(const bf16x8*)&Bs[nf * 16 + (lane & 15)][(lane >> 4) * 8];
#pragma unroll
    for (int mf = 0; mf < 4; ++mf)
#pragma unroll
      for (int nf = 0; nf < 4; ++nf)
        acc[mf][nf] = __builtin_amdgcn_mfma_f32_16x16x32_bf16(af[mf], bf[nf],
                                                              acc[mf][nf], 0, 0, 0);
  }

#pragma unroll
  for (int mf = 0; mf < 4; ++mf)
#pragma unroll
    for (int nf = 0; nf < 4; ++nf)
#pragma unroll
      for (int r = 0; r < 4; ++r) {
        int row = w * 64 + mf * 16 + (lane >> 4) * 4 + r;
        int col = bn + nf * 16 + (lane & 15);
        out[row * NCOLS + col] = acc[mf][nf][r];
      }
}

// ---------------------------------------------------------------------------
extern "C" void kernel_launch(void* const* d_in, const int* in_sizes, int n_in,
                              void* d_out, int out_size, void* d_ws, size_t ws_size,
                              hipStream_t stream) {
  const float* X = (const float*)d_in[0];
  const float* W = (const float*)d_in[1];
  const float* Dp = (const float*)d_in[2];
  float* out = (float*)d_out;

  char* ws = (char*)d_ws;
  double* G = (double*)ws;                          // 2 MB: Gram -> L (f64)
  float* Lf = (float*)(ws + (2u << 20));            // 1 MB: L (f32, row-major)
  float* Minv = (float*)(ws + (3u << 20));          // 1 MB: L^-1 (f32)
  float* U = (float*)(ws + (4u << 20));             // 1 MB
  unsigned short* P = (unsigned short*)(ws + (5u << 20));  // 0.5 MB bf16
  float* T = (float*)ws;  // comb temp ALIASES G (G dead before comb runs)

  k_gram<<<dim3(16, 16), 256, 0, stream>>>(W, G);
  hipMemsetAsync(Minv, 0, DIM * DIM * sizeof(float), stream);
  for (int k = 0; k < 8; ++k) {
    k_panel<<<1, 512, 0, stream>>>(G, Lf, k);
    int rem = 7 - k;
    if (rem > 0) {
      int m = rem * 64;
      k_syrk<<<dim3(m / 16, m / 16), 256, 0, stream>>>(G, k);
    }
  }
  k_dinv<<<8, 64, 0, stream>>>(Lf, Minv);
  for (int l = 0; l < 3; ++l) {
    int n = 64 << l, Pn = 4 >> l;
    k_combT<<<dim3(n / 16, n / 16, Pn), 256, 0, stream>>>(Lf, Minv, T, n);
    k_combO<<<dim3(n / 16, n / 16, Pn), 256, 0, stream>>>(Minv, T, n);
  }
  k_formU<<<dim3(32, 32), 256, 0, stream>>>(W, Minv, U);
  k_formP<<<dim3(32, 32), 256, 0, stream>>>(U, Dp, P);
  k_gemm<<<NCOLS / 64, 512, 0, stream>>>(P, X, out);
}

// Round 5
// 750.152 us; speedup vs baseline: 3.1008x; 1.2082x over previous
//
#include <hip/hip_runtime.h>
#include <hip/hip_bf16.h>

#define DIM 512
#define NCOLS 16384

typedef __bf16 bf16x8 __attribute__((ext_vector_type(8)));
typedef float f32x4 __attribute__((ext_vector_type(4)));

__device__ __forceinline__ unsigned short f2bf(float f) {
  unsigned u = __builtin_bit_cast(unsigned, f);
  u += 0x7FFFu + ((u >> 16) & 1u);
  return (unsigned short)(u >> 16);
}

// ---------------------------------------------------------------------------
// Stage 1 (r5 REWRITE): G = W^T W, f64 accumulate, LDS-tiled (coalesced).
// 32x32 output tile / block, 2x2 micro, K-chunk 16 over rows of W.
__global__ __launch_bounds__(256) void k_gram(const float* __restrict__ W,
                                              double* __restrict__ G) {
  __shared__ float Wa[16][34];  // [r][i-local], pad->34 for aligned float2
  __shared__ float Wb[16][34];  // [r][j-local]
  const int t = threadIdx.x;
  const int tx = t & 15, ty = t >> 4;
  const int i0 = blockIdx.y * 32, j0 = blockIdx.x * 32;
  const int rr = t >> 4, c2 = (t & 15) * 2;  // staging coords
  double acc[2][2] = {{0, 0}, {0, 0}};

  for (int kr = 0; kr < DIM; kr += 16) {
    __syncthreads();
    *(float2*)&Wa[rr][c2] = *(const float2*)&W[(kr + rr) * DIM + i0 + c2];
    *(float2*)&Wb[rr][c2] = *(const float2*)&W[(kr + rr) * DIM + j0 + c2];
    __syncthreads();
#pragma unroll
    for (int r = 0; r < 16; ++r) {
      float2 wi = *(const float2*)&Wa[r][ty * 2];
      float2 wj = *(const float2*)&Wb[r][tx * 2];
      acc[0][0] += (double)wi.x * (double)wj.x;
      acc[0][1] += (double)wi.x * (double)wj.y;
      acc[1][0] += (double)wi.y * (double)wj.x;
      acc[1][1] += (double)wi.y * (double)wj.y;
    }
  }
#pragma unroll
  for (int a = 0; a < 2; ++a)
#pragma unroll
    for (int b = 0; b < 2; ++b)
      G[(i0 + ty * 2 + a) * DIM + j0 + tx * 2 + b] = acc[a][b];
}

// ---------------------------------------------------------------------------
// Stage 2: fused per-panel kernel (unchanged from r4).
__global__ __launch_bounds__(512) void k_panel(double* __restrict__ G,
                                               float* __restrict__ Lf,
                                               int k) {
  __shared__ double A[64][65];
  __shared__ double invd[64];
  const int tid = threadIdx.x;
  const int base = k * 64;

  for (int e = tid; e < 4096; e += 512) {
    int i = e >> 6, j = e & 63;
    A[i][j] = G[(base + i) * DIM + base + j];
  }
  __syncthreads();

#pragma unroll 1
  for (int c = 0; c < 64; ++c) {
    double inv = 1.0 / A[c][c];
#pragma unroll
    for (int q = 0; q < 8; ++q) {
      int e = q * 512 + tid;
      int i = e >> 6, j = e & 63;
      if (j > c && i >= j)
        A[i][j] -= A[i][c] * (A[j][c] * inv);
    }
    __syncthreads();
    double rs = sqrt(inv);
    if (tid == c) invd[c] = rs;
    if (tid < 64 && tid >= c) A[tid][c] *= rs;
  }
  __syncthreads();

  for (int e = tid; e < 4096; e += 512) {
    int i = e >> 6, j = e & 63;
    Lf[(base + i) * DIM + base + j] = (i >= j) ? (float)A[i][j] : 0.f;
  }

  const int r = base + 64 + tid;
  if (r < DIM) {
    double x[64];
#pragma unroll
    for (int j = 0; j < 64; ++j) x[j] = G[r * DIM + base + j];
#pragma unroll
    for (int j = 0; j < 64; ++j) {
      double s0 = 0, s1 = 0, s2 = 0, s3 = 0;
#pragma unroll
      for (int c = 0; c < j; ++c) {
        double t = x[c] * A[j][c];
        if ((c & 3) == 0) s0 += t;
        else if ((c & 3) == 1) s1 += t;
        else if ((c & 3) == 2) s2 += t;
        else s3 += t;
      }
      x[j] = (x[j] - ((s0 + s1) + (s2 + s3))) * invd[j];
    }
#pragma unroll
    for (int j = 0; j < 64; ++j) {
      G[r * DIM + base + j] = x[j];
      Lf[r * DIM + base + j] = (float)x[j];
    }
  }
}

// ---------------------------------------------------------------------------
// Stage 2c (r5 REWRITE): Schur update, LDS-tiled f64.  32x32 tile, 2x2 micro.
// LDS transposed [c][row-local], pad->34 so b128 (double2) reads are aligned;
// lanes tx and tx+8 share banks = 2-way = free.
__global__ __launch_bounds__(256) void k_syrk(double* __restrict__ G, int k) {
  __shared__ double Lat[64][34];  // [c][i-local]
  __shared__ double Lbt[64][34];  // [c][j-local]
  const int off = (k + 1) * 64, pb = k * 64;
  const int t = threadIdx.x;
  const int bx = blockIdx.x, by = blockIdx.y;
  if (bx > by) return;  // strictly-upper tile: skip
  const int j0 = off + bx * 32, i0 = off + by * 32;
  const int tx = t & 15, ty = t >> 4;

  {  // stage: 32 rows x 64 c per tile; thread: row t>>3, 8 c's at (t&7)*8
    const int ii = t >> 3, c0 = (t & 7) * 8;
    const double* gi = &G[(i0 + ii) * DIM + pb + c0];
    const double* gj = &G[(j0 + ii) * DIM + pb + c0];
#pragma unroll
    for (int q = 0; q < 4; ++q) {
      double2 va = *(const double2*)(gi + 2 * q);
      double2 vb = *(const double2*)(gj + 2 * q);
      Lat[c0 + 2 * q][ii] = va.x; Lat[c0 + 2 * q + 1][ii] = va.y;
      Lbt[c0 + 2 * q][ii] = vb.x; Lbt[c0 + 2 * q + 1][ii] = vb.y;
    }
  }
  __syncthreads();

  double acc[2][2] = {{0, 0}, {0, 0}};
#pragma unroll 8
  for (int c = 0; c < 64; ++c) {
    double2 la = *(const double2*)&Lat[c][ty * 2];
    double2 lb = *(const double2*)&Lbt[c][tx * 2];
    acc[0][0] += la.x * lb.x; acc[0][1] += la.x * lb.y;
    acc[1][0] += la.y * lb.x; acc[1][1] += la.y * lb.y;
  }
#pragma unroll
  for (int a = 0; a < 2; ++a)
#pragma unroll
    for (int b = 0; b < 2; ++b) {
      int i = i0 + ty * 2 + a, j = j0 + tx * 2 + b;
      G[i * DIM + j] -= acc[a][b];  // upper-within-diag-tile garbage is unused
    }
}

// ---------------------------------------------------------------------------
// Stage 3a: invert the 8 diagonal 64x64 blocks of L (unchanged from r4).
__global__ __launch_bounds__(64) void k_dinv(const float* __restrict__ Lf,
                                             float* __restrict__ Minv) {
  __shared__ float Ld[64][65];
  const int lane = threadIdx.x;
  const int b = blockIdx.x * 64;
  for (int r = 0; r < 64; ++r) Ld[r][lane] = Lf[(b + r) * DIM + b + lane];
  __syncthreads();
  float y[64];
#pragma unroll
  for (int i = 0; i < 64; ++i) {
    float s = (i == lane) ? 1.f : 0.f;
#pragma unroll
    for (int c = 0; c < i; ++c) s -= Ld[i][c] * y[c];
    y[i] = s / Ld[i][i];
  }
  for (int i = 0; i < 64; ++i) Minv[(b + i) * DIM + b + lane] = y[i];
}

// ---------------------------------------------------------------------------
// Stage 3b: recursive combine (unchanged from r4).
__global__ __launch_bounds__(256) void k_combT(const float* __restrict__ Lf,
                                               const float* __restrict__ Minv,
                                               float* __restrict__ T, int n) {
  const int p = blockIdx.z;
  const int rb = p * 2 * n + n, cb = p * 2 * n;
  const int j = blockIdx.x * 16 + (threadIdx.x & 15);
  const int i = blockIdx.y * 16 + (threadIdx.x >> 4);
  float acc = 0.f;
#pragma unroll 4
  for (int c = 0; c < n; ++c)
    acc += Lf[(rb + i) * DIM + cb + c] * Minv[(cb + c) * DIM + cb + j];
  T[p * n * n + i * n + j] = acc;
}

__global__ __launch_bounds__(256) void k_combO(float* __restrict__ Minv,
                                               const float* __restrict__ T, int n) {
  const int p = blockIdx.z;
  const int rb = p * 2 * n + n, cb = p * 2 * n;
  const int j = blockIdx.x * 16 + (threadIdx.x & 15);
  const int i = blockIdx.y * 16 + (threadIdx.x >> 4);
  float acc = 0.f;
#pragma unroll 4
  for (int c = 0; c < n; ++c)
    acc += Minv[(rb + i) * DIM + rb + c] * T[p * n * n + c * n + j];
  Minv[(rb + i) * DIM + cb + j] = -acc;
}

// ---------------------------------------------------------------------------
// Stage 4 (r5 REWRITE): U = W * Minv^T, LDS-tiled f32.  32x32 tile, 2x2 micro.
// Both operands row-major in the contraction index c -> coalesced staging;
// LDS transposed [c][local], pad->34 for aligned float2 reads.
__global__ __launch_bounds__(256) void k_formU(const float* __restrict__ W,
                                               const float* __restrict__ Minv,
                                               float* __restrict__ U) {
  __shared__ float Wt[32][34];  // [c][r-local]
  __shared__ float Mt[32][34];  // [c][i-local]
  const int t = threadIdx.x;
  const int tx = t & 15, ty = t >> 4;
  const int i0 = blockIdx.x * 32, r0 = blockIdx.y * 32;
  const int sr = t >> 3, sc = (t & 7) * 4;  // staging: row-local, 4 c's
  float acc[2][2] = {{0, 0}, {0, 0}};

  for (int kc = 0; kc < DIM; kc += 32) {
    __syncthreads();
    float4 vw = *(const float4*)&W[(r0 + sr) * DIM + kc + sc];
    float4 vm = *(const float4*)&Minv[(i0 + sr) * DIM + kc + sc];
    Wt[sc + 0][sr] = vw.x; Wt[sc + 1][sr] = vw.y;
    Wt[sc + 2][sr] = vw.z; Wt[sc + 3][sr] = vw.w;
    Mt[sc + 0][sr] = vm.x; Mt[sc + 1][sr] = vm.y;
    Mt[sc + 2][sr] = vm.z; Mt[sc + 3][sr] = vm.w;
    __syncthreads();
#pragma unroll 8
    for (int c = 0; c < 32; ++c) {
      float2 wv = *(const float2*)&Wt[c][ty * 2];
      float2 mv = *(const float2*)&Mt[c][tx * 2];
      acc[0][0] += wv.x * mv.x; acc[0][1] += wv.x * mv.y;
      acc[1][0] += wv.y * mv.x; acc[1][1] += wv.y * mv.y;
    }
  }
#pragma unroll
  for (int a = 0; a < 2; ++a)
#pragma unroll
    for (int b = 0; b < 2; ++b)
      U[(r0 + ty * 2 + a) * DIM + i0 + tx * 2 + b] = acc[a][b];
}

// ---------------------------------------------------------------------------
// Stage 5 (r5 REWRITE): P = U*diag(sigmoid(Dp))*U^T via bf16 MFMA.
// 64x64 tile / block (grid 8x8), 4 waves, wave w = 16-row stripe, K=512.
// A[i][c] = U[i][c]*sig(D[c]) (bf16), B[j][c] = U[j][c] (bf16), acc f32.
__global__ __launch_bounds__(256) void k_formP(const float* __restrict__ Uin,
                                               const float* __restrict__ Dp,
                                               unsigned short* __restrict__ P) {
  __shared__ float dsh[DIM];
  __shared__ unsigned short As[64][40];
  __shared__ unsigned short Bs[64][40];
  const int t = threadIdx.x;
  const int lane = t & 63, w = t >> 6;
  const int i0 = blockIdx.y * 64, j0 = blockIdx.x * 64;
  const int row = t >> 2, seg = t & 3;  // staging: row-local, 8 c's at seg*8

  dsh[t] = 1.f / (1.f + __expf(-Dp[t]));
  dsh[t + 256] = 1.f / (1.f + __expf(-Dp[t + 256]));

  f32x4 acc[4];
#pragma unroll
  for (int nf = 0; nf < 4; ++nf) acc[nf] = (f32x4){0.f, 0.f, 0.f, 0.f};

#pragma unroll 1
  for (int kc = 0; kc < DIM; kc += 32) {
    __syncthreads();  // also covers initial dsh fill
    const int c0 = kc + seg * 8;
    float4 ua = *(const float4*)&Uin[(i0 + row) * DIM + c0];
    float4 ub = *(const float4*)&Uin[(i0 + row) * DIM + c0 + 4];
    float4 va = *(const float4*)&Uin[(j0 + row) * DIM + c0];
    float4 vb = *(const float4*)&Uin[(j0 + row) * DIM + c0 + 4];
    uint4 pa, pb;
    pa.x = (unsigned)f2bf(ua.x * dsh[c0 + 0]) | ((unsigned)f2bf(ua.y * dsh[c0 + 1]) << 16);
    pa.y = (unsigned)f2bf(ua.z * dsh[c0 + 2]) | ((unsigned)f2bf(ua.w * dsh[c0 + 3]) << 16);
    pa.z = (unsigned)f2bf(ub.x * dsh[c0 + 4]) | ((unsigned)f2bf(ub.y * dsh[c0 + 5]) << 16);
    pa.w = (unsigned)f2bf(ub.z * dsh[c0 + 6]) | ((unsigned)f2bf(ub.w * dsh[c0 + 7]) << 16);
    pb.x = (unsigned)f2bf(va.x) | ((unsigned)f2bf(va.y) << 16);
    pb.y = (unsigned)f2bf(va.z) | ((unsigned)f2bf(va.w) << 16);
    pb.z = (unsigned)f2bf(vb.x) | ((unsigned)f2bf(vb.y) << 16);
    pb.w = (unsigned)f2bf(vb.z) | ((unsigned)f2bf(vb.w) << 16);
    *(uint4*)&As[row][seg * 8] = pa;
    *(uint4*)&Bs[row][seg * 8] = pb;
    __syncthreads();
    bf16x8 af = *(const bf16x8*)&As[w * 16 + (lane & 15)][(lane >> 4) * 8];
#pragma unroll
    for (int nf = 0; nf < 4; ++nf) {
      bf16x8 bf = *(const bf16x8*)&Bs[nf * 16 + (lane & 15)][(lane >> 4) * 8];
      acc[nf] = __builtin_amdgcn_mfma_f32_16x16x32_bf16(af, bf, acc[nf], 0, 0, 0);
    }
  }
#pragma unroll
  for (int nf = 0; nf < 4; ++nf)
#pragma unroll
    for (int r = 0; r < 4; ++r) {
      int ri = i0 + w * 16 + (lane >> 4) * 4 + r;
      int cj = j0 + nf * 16 + (lane & 15);
      P[ri * DIM + cj] = f2bf(acc[nf][r]);
    }
}

// ---------------------------------------------------------------------------
// Stage 6: out = P @ x via bf16 MFMA (unchanged from r3/r4).
__global__ __launch_bounds__(512) void k_gemm(const unsigned short* __restrict__ P,
                                              const float* __restrict__ X,
                                              float* __restrict__ out) {
  __shared__ unsigned short As[DIM][40];
  __shared__ unsigned short Bs[64][40];
  const int tid = threadIdx.x;
  const int lane = tid & 63;
  const int w = tid >> 6;
  const int bn = blockIdx.x * 64;
  const int kk = tid >> 4;
  const int nq = tid & 15;

  const unsigned short* prow = P + tid * DIM;
  uint4 a0 = *(const uint4*)(prow + 0);
  uint4 a1 = *(const uint4*)(prow + 8);
  uint4 a2 = *(const uint4*)(prow + 16);
  uint4 a3 = *(const uint4*)(prow + 24);
  float4 bx = *(const float4*)(X + kk * NCOLS + bn + nq * 4);

  f32x4 acc[4][4];
#pragma unroll
  for (int mf = 0; mf < 4; ++mf)
#pragma unroll
    for (int nf = 0; nf < 4; ++nf)
      acc[mf][nf] = (f32x4){0.f, 0.f, 0.f, 0.f};

#pragma unroll 1
  for (int t = 0; t < 16; ++t) {
    __syncthreads();
    *(uint4*)&As[tid][0] = a0;
    *(uint4*)&As[tid][8] = a1;
    *(uint4*)&As[tid][16] = a2;
    *(uint4*)&As[tid][24] = a3;
    Bs[nq * 4 + 0][kk] = f2bf(bx.x);
    Bs[nq * 4 + 1][kk] = f2bf(bx.y);
    Bs[nq * 4 + 2][kk] = f2bf(bx.z);
    Bs[nq * 4 + 3][kk] = f2bf(bx.w);
    if (t < 15) {
      const unsigned short* pn = prow + (t + 1) * 32;
      a0 = *(const uint4*)(pn + 0);
      a1 = *(const uint4*)(pn + 8);
      a2 = *(const uint4*)(pn + 16);
      a3 = *(const uint4*)(pn + 24);
      bx = *(const float4*)(X + ((t + 1) * 32 + kk) * NCOLS + bn + nq * 4);
    }
    __syncthreads();
    bf16x8 af[4], bf[4];
#pragma unroll
    for (int mf = 0; mf < 4; ++mf)
      af[mf] = *(const bf16x8*)&As[w * 64 + mf * 16 + (lane & 15)][(lane >> 4) * 8];
#pragma unroll
    for (int nf = 0; nf < 4; ++nf)
      bf[nf] = *(const bf16x8*)&Bs[nf * 16 + (lane & 15)][(lane >> 4) * 8];
#pragma unroll
    for (int mf = 0; mf < 4; ++mf)
#pragma unroll
      for (int nf = 0; nf < 4; ++nf)
        acc[mf][nf] = __builtin_amdgcn_mfma_f32_16x16x32_bf16(af[mf], bf[nf],
                                                              acc[mf][nf], 0, 0, 0);
  }

#pragma unroll
  for (int mf = 0; mf < 4; ++mf)
#pragma unroll
    for (int nf = 0; nf < 4; ++nf)
#pragma unroll
      for (int r = 0; r < 4; ++r) {
        int row = w * 64 + mf * 16 + (lane >> 4) * 4 + r;
        int col = bn + nf * 16 + (lane & 15);
        out[row * NCOLS + col] = acc[mf][nf][r];
      }
}

// ---------------------------------------------------------------------------
extern "C" void kernel_launch(void* const* d_in, const int* in_sizes, int n_in,
                              void* d_out, int out_size, void* d_ws, size_t ws_size,
                              hipStream_t stream) {
  const float* X = (const float*)d_in[0];
  const float* W = (const float*)d_in[1];
  const float* Dp = (const float*)d_in[2];
  float* out = (float*)d_out;

  char* ws = (char*)d_ws;
  double* G = (double*)ws;                          // 2 MB: Gram -> L (f64)
  float* Lf = (float*)(ws + (2u << 20));            // 1 MB: L (f32, row-major)
  float* Minv = (float*)(ws + (3u << 20));          // 1 MB: L^-1 (f32)
  float* U = (float*)(ws + (4u << 20));             // 1 MB
  unsigned short* P = (unsigned short*)(ws + (5u << 20));  // 0.5 MB bf16
  float* T = (float*)ws;  // comb temp ALIASES G (G dead before comb runs)

  k_gram<<<dim3(16, 16), 256, 0, stream>>>(W, G);
  hipMemsetAsync(Minv, 0, DIM * DIM * sizeof(float), stream);
  for (int k = 0; k < 8; ++k) {
    k_panel<<<1, 512, 0, stream>>>(G, Lf, k);
    int rem = 7 - k;
    if (rem > 0)
      k_syrk<<<dim3(rem * 2, rem * 2), 256, 0, stream>>>(G, k);
  }
  k_dinv<<<8, 64, 0, stream>>>(Lf, Minv);
  for (int l = 0; l < 3; ++l) {
    int n = 64 << l, Pn = 4 >> l;
    k_combT<<<dim3(n / 16, n / 16, Pn), 256, 0, stream>>>(Lf, Minv, T, n);
    k_combO<<<dim3(n / 16, n / 16, Pn), 256, 0, stream>>>(Minv, T, n);
  }
  k_formU<<<dim3(16, 16), 256, 0, stream>>>(W, Minv, U);
  k_formP<<<dim3(8, 8), 256, 0, stream>>>(U, Dp, P);
  k_gemm<<<NCOLS / 64, 512, 0, stream>>>(P, X, out);
}